// Round 8
// baseline (274.058 us; speedup 1.0000x reference)
//
#include <hip/hip_runtime.h>
#include <math.h>

#define B_SZ 16384
#define F_N 39
#define V_N 30000
#define D_N 16
#define K_SEL 20
#define FD 624     // F_N * D_N
#define KP0 640    // controller/GEMM0 K padded to multiple of 32
#define NCP 48     // controller GEMM padded N (>= 39, 3 n-tiles of 16)
#define N0 1024
#define N1 512
#define CBR 16     // batch rows per fused-controller block
#define ALD 648    // LDS row stride (u16)
#define SLOT 9216  // fused-MLP staging slot size in u16 (A 1024 + B 8192)

typedef unsigned short u16;
typedef __attribute__((ext_vector_type(8))) short bf16x8;
typedef __attribute__((ext_vector_type(8))) unsigned short u16x8;
typedef __attribute__((ext_vector_type(4))) float f32x4;

__device__ __forceinline__ float bf2f(u16 v) {
    union { unsigned u; float f; } x; x.u = ((unsigned)v) << 16;
    return x.f;
}
// HW packed convert: D[15:0]=bf16(a), D[31:16]=bf16(b), RNE.
__device__ __forceinline__ unsigned cvtpk2(float a, float b) {
    unsigned d;
    asm("v_cvt_pk_bf16_f32 %0, %1, %2" : "=v"(d) : "v"(a), "v"(b));
    return d;
}

#define GLD16(gp, lp) __builtin_amdgcn_global_load_lds( \
    (const __attribute__((address_space(1))) unsigned int*)(gp), \
    (__attribute__((address_space(3))) unsigned int*)(lp), 16, 0, 0)

#define MFMA16(a, b, c) __builtin_amdgcn_mfma_f32_16x16x32_bf16((a), (b), (c), 0, 0, 0)

// ---------------------------------------------------------------------------
// prep (coalesced): [0,134) w0/wc permute via LDS; [134,390) w1 convert;
// 390: bn param vectors.
// ---------------------------------------------------------------------------
__global__ __launch_bounds__(256) void prep_all_kernel(
    const float* __restrict__ w0, const float* __restrict__ w1,
    const float* __restrict__ w_c, const float* __restrict__ b_c,
    const float* __restrict__ g_c, const float* __restrict__ be_c,
    u16* __restrict__ w0b, u16* __restrict__ w1b, u16* __restrict__ wcb,
    float* __restrict__ bcp, float* __restrict__ gcp, float* __restrict__ becp)
{
    __shared__ float Lb[8][624];
    const int bid = blockIdx.x;
    const int t   = threadIdx.x;

    if (bid < 134) {                       // w0 (bid<128) or wc permute
        const bool is_w0 = (bid < 128);
        const int r0 = is_w0 ? bid * 8 : (bid - 128) * 8;
        const int nrows_src = is_w0 ? N0 : F_N;
        const float* __restrict__ src = is_w0 ? w0 : w_c;
        u16* __restrict__ dst = is_w0 ? w0b : wcb;

        for (int j = t; j < 8 * 156; j += 256) {
            const int row = j / 156;
            const int c4  = j - row * 156;
            const int n   = r0 + row;
            if (n < nrows_src)
                *(float4*)&Lb[row][c4 * 4] =
                    *(const float4*)&src[(size_t)n * FD + c4 * 4];
        }
        __syncthreads();

        for (int j = t; j < 8 * 320; j += 256) {
            const int row = j / 320;
            const int pr  = j - row * 320;
            const int n   = r0 + row;
            const int k0  = pr * 2;
            float v0 = 0.f, v1 = 0.f;
            if (n < nrows_src) {
                const int d0 = k0 & 15,       f0 = k0 >> 4;
                const int d1 = (k0 + 1) & 15, f1 = (k0 + 1) >> 4;
                if (f0 < F_N) v0 = Lb[row][d0 * F_N + f0];
                if (f1 < F_N) v1 = Lb[row][d1 * F_N + f1];
            }
            *(unsigned*)&dst[(size_t)n * KP0 + k0] = cvtpk2(v0, v1);
        }
        return;
    }
    if (bid < 390) {                       // w1 convert
        const size_t e0 = (size_t)(bid - 134) * 2048 + t * 8;
        float4 v0 = *(const float4*)(w1 + e0);
        float4 v1 = *(const float4*)(w1 + e0 + 4);
        uint4 o = { cvtpk2(v0.x, v0.y), cvtpk2(v0.z, v0.w),
                    cvtpk2(v1.x, v1.y), cvtpk2(v1.z, v1.w) };
        *(uint4*)(w1b + e0) = o;
        return;
    }
    // bid == 390: bn params
    if (t < 3 * NCP) {
        const int which = t / NCP, n = t - which * NCP;
        float v = 0.f;
        if (n < F_N) v = (which == 0) ? b_c[n] : (which == 1) ? g_c[n] : be_c[n];
        ((which == 0) ? bcp : (which == 1) ? gcp : becp)[n] = v;
    }
}

// ---------------------------------------------------------------------------
// Fused controller (proven r3 version, unchanged).
// ---------------------------------------------------------------------------
__global__ __launch_bounds__(256) void fused_controller_kernel(
    const int* __restrict__ x, const float* __restrict__ emb_table,
    const u16* __restrict__ wcb, const float* __restrict__ bcp,
    const float* __restrict__ gcp, const float* __restrict__ becp,
    u16* __restrict__ zb)
{
    __shared__ __align__(16) u16 Al[CBR * ALD];
    __shared__ float vv[CBR][49];
    __shared__ f32x4 part[4][64][3];
    __shared__ float selw[CBR][F_N];

    const int t    = threadIdx.x;
    const int wave = t >> 6;
    const int lane = t & 63;
    const int b0   = blockIdx.x * CBR;

    {
        const int p0 = t, p1 = t + 256, p2 = t + 512;
        const int xi0 = x[b0 * F_N + p0];
        const int xi1 = x[b0 * F_N + p1];
        const int xi2 = (p2 < CBR * F_N) ? x[b0 * F_N + p2] : 0;
        const int pp[3] = { p0, p1, p2 };
        const int xx[3] = { xi0, xi1, xi2 };
        #pragma unroll
        for (int s = 0; s < 3; ++s) {
            const int p = pp[s];
            if (p < CBR * F_N) {
                const int row = p / F_N;
                const int f   = p - row * F_N;
                const float4* src =
                    (const float4*)(emb_table + (size_t)(xx[s] + f * V_N) * D_N);
                float4 v0 = src[0], v1 = src[1], v2 = src[2], v3 = src[3];
                uint4 o0 = { cvtpk2(v0.x, v0.y), cvtpk2(v0.z, v0.w),
                             cvtpk2(v1.x, v1.y), cvtpk2(v1.z, v1.w) };
                uint4 o1 = { cvtpk2(v2.x, v2.y), cvtpk2(v2.z, v2.w),
                             cvtpk2(v3.x, v3.y), cvtpk2(v3.z, v3.w) };
                *(uint4*)&Al[row * ALD + f * D_N]     = o0;
                *(uint4*)&Al[row * ALD + f * D_N + 8] = o1;
            }
        }
    }
    __syncthreads();

    const int m = lane & 15;
    const int q = lane >> 4;
    f32x4 acc0 = {}, acc1 = {}, acc2 = {};
    {
        const u16* ap  = &Al[m * ALD + wave * 160 + q * 8];
        const u16* bp0 = wcb + (size_t)(0  + m) * KP0 + wave * 160 + q * 8;
        const u16* bp1 = wcb + (size_t)(16 + m) * KP0 + wave * 160 + q * 8;
        const u16* bp2 = wcb + (size_t)(32 + m) * KP0 + wave * 160 + q * 8;
        #pragma unroll
        for (int k = 0; k < 5; ++k) {
            bf16x8 af = *(const bf16x8*)ap;
            bf16x8 b0r = *(const bf16x8*)bp0;
            bf16x8 b1r = *(const bf16x8*)bp1;
            bf16x8 b2r = *(const bf16x8*)bp2;
            acc0 = MFMA16(af, b0r, acc0);
            acc1 = MFMA16(af, b1r, acc1);
            acc2 = MFMA16(af, b2r, acc2);
            ap += 32; bp0 += 32; bp1 += 32; bp2 += 32;
        }
    }
    part[wave][lane][0] = acc0;
    part[wave][lane][1] = acc1;
    part[wave][lane][2] = acc2;
    __syncthreads();

    {
        f32x4 r0 = part[0][lane][0] + part[1][lane][0] + part[2][lane][0] + part[3][lane][0];
        f32x4 r1 = part[0][lane][1] + part[1][lane][1] + part[2][lane][1] + part[3][lane][1];
        f32x4 r2 = part[0][lane][2] + part[1][lane][2] + part[2][lane][2] + part[3][lane][2];

        const float rs = rsqrtf(1.0f + 1e-5f);
        if (q == wave) {
            #pragma unroll
            for (int j = 0; j < 3; ++j) {
                const f32x4 a = (j == 0) ? r0 : (j == 1) ? r1 : r2;
                const int n = j * 16 + m;
                const float gn = gcp[n] * rs;
                const float bn = becp[n];
                const float bi = bcp[n];
                #pragma unroll
                for (int r = 0; r < 4; ++r)
                    vv[wave * 4 + r][n] = fmaxf(fmaf(gn, a[r] + bi, bn), 0.f);
            }
        }
    }
    __syncthreads();

    {
        const int row = wave * 4 + (lane >> 4);
        const int fl  = lane & 15;
        float e[3] = {0.f, 0.f, 0.f};
        float mloc = -1e30f;
        #pragma unroll
        for (int it = 0; it < 3; ++it) {
            const int f = fl + 16 * it;
            if (f < F_N) { e[it] = vv[row][f]; mloc = fmaxf(mloc, e[it]); }
        }
        mloc = fmaxf(mloc, __shfl_xor(mloc, 1, 64));
        mloc = fmaxf(mloc, __shfl_xor(mloc, 2, 64));
        mloc = fmaxf(mloc, __shfl_xor(mloc, 4, 64));
        mloc = fmaxf(mloc, __shfl_xor(mloc, 8, 64));
        float sloc = 0.f;
        #pragma unroll
        for (int it = 0; it < 3; ++it) {
            const int f = fl + 16 * it;
            if (f < F_N) { e[it] = expf(e[it] - mloc); sloc += e[it]; }
        }
        sloc += __shfl_xor(sloc, 1, 64);
        sloc += __shfl_xor(sloc, 2, 64);
        sloc += __shfl_xor(sloc, 4, 64);
        sloc += __shfl_xor(sloc, 8, 64);
        const float inv = 1.f / sloc;
        #pragma unroll
        for (int it = 0; it < 3; ++it) {
            const int f = fl + 16 * it;
            if (f < F_N) vv[row][f] = e[it];
        }

        int rank[3] = {};
        for (int gg = 0; gg < F_N; ++gg) {
            const float o = vv[row][gg];
            #pragma unroll
            for (int it = 0; it < 3; ++it) {
                const int f = fl + 16 * it;
                if (f < F_N)
                    rank[it] += (o > e[it] || (o == e[it] && gg < f)) ? 1 : 0;
            }
        }
        #pragma unroll
        for (int it = 0; it < 3; ++it) {
            const int f = fl + 16 * it;
            if (f < F_N)
                selw[row][f] = (rank[it] < K_SEL) ? e[it] * inv : 0.f;
        }
    }
    __syncthreads();

    for (int gp = t; gp < CBR * 40; gp += 256) {
        const int row  = gp / 40;
        const int slot = gp - row * 40;
        u16* dst = zb + (size_t)(b0 + row) * KP0 + slot * D_N;
        uint4 o0 = {0u,0u,0u,0u}, o1 = {0u,0u,0u,0u};
        if (slot < F_N) {
            const float w = selw[row][slot];
            u16x8 a0 = *(u16x8*)&Al[row * ALD + slot * D_N];
            u16x8 a1 = *(u16x8*)&Al[row * ALD + slot * D_N + 8];
            o0 = (uint4){ cvtpk2(bf2f(a0[0]) * w, bf2f(a0[1]) * w),
                          cvtpk2(bf2f(a0[2]) * w, bf2f(a0[3]) * w),
                          cvtpk2(bf2f(a0[4]) * w, bf2f(a0[5]) * w),
                          cvtpk2(bf2f(a0[6]) * w, bf2f(a0[7]) * w) };
            o1 = (uint4){ cvtpk2(bf2f(a1[0]) * w, bf2f(a1[1]) * w),
                          cvtpk2(bf2f(a1[2]) * w, bf2f(a1[3]) * w),
                          cvtpk2(bf2f(a1[4]) * w, bf2f(a1[5]) * w),
                          cvtpk2(bf2f(a1[6]) * w, bf2f(a1[7]) * w) };
        }
        *(uint4*)dst       = o0;
        *(uint4*)(dst + 8) = o1;
    }
}

// ---------------------------------------------------------------------------
// Fused MLP v2: 32 batch rows/block, grid 512, 72 KB LDS -> 2 blocks/CU
// (r7 diagnosis: 133 KB -> 1 block/CU -> 22% occupancy, all stalls exposed).
// Per block, for nt in 0..3 (h0 col-chunks of 256):
//   phase A (20 steps, BK=32): h0c = relu(bn0(zb[32x640] @ w0b-chunk^T));
//     3-slot counted-vmcnt pipeline; waves 0-1 stage A+B (vmcnt 3),
//     waves 2-7 stage B only (vmcnt 2).
//   h0c -> H0 LDS bf16 [32][256], XOR-swizzled (chunk ^= row&7): kills the
//     524K bank conflicts of r7's stride-264 layout (2-way = free).
//   phase B: 2 halves of N1=256 cols x 8 steps (BK=32), uniform vmcnt(2);
//     A-frags ds_read from H0, B staged from w1b; acc1[2][4] per thread
//     (h unrolled -- rule #20). Phase-B prologue issued before the h0
//     epilogue so HBM latency hides under it (T14).
// Final: bn1/relu/w_out dot, shuffle+LDS reduce, sigmoid -> out.
// h0 never touches HBM; numerics identical to r7 (passed absmax 0).
// ---------------------------------------------------------------------------
__global__ __launch_bounds__(512) void fused_mlp_kernel(
    const u16* __restrict__ Azb, const u16* __restrict__ W0,
    const u16* __restrict__ W1,
    const float* __restrict__ b0v, const float* __restrict__ g0v,
    const float* __restrict__ be0v,
    const float* __restrict__ b1v, const float* __restrict__ g1v,
    const float* __restrict__ be1v,
    const float* __restrict__ wov, const float* __restrict__ bov,
    float* __restrict__ out)
{
    // 3 slots x 9216 u16 (A 1024 + B 8192) + H0 8192 u16 = 71680 B
    __shared__ __align__(16) u16 SM[3 * SLOT + 32 * 256];
    __shared__ float red[4][32];

    const int t    = threadIdx.x;
    const int lane = t & 63;
    const int wave = t >> 6;
    const int wm = wave >> 2, wn = wave & 3;      // 2 m-waves x 4 n-waves
    const int q = lane >> 4, lr16 = lane & 15;
    const int brow = blockIdx.x * 32;

    u16* const H0 = SM + 3 * SLOT;

    // staging addressing: row = t>>2, chunk-swizzle cA = (t&3)^((row>>1)&3),
    // linear LDS dest (t*8). Read side applies the matching XOR.
    const int rS = t >> 2;
    const int cA = (t & 3) ^ ((rS >> 1) & 3);

    // ds_read offsets
    const int raA   = wm * 16 + lr16;                       // A row (batch)
    const int aoffA = raA * 32 + ((q ^ ((raA >> 1) & 3)) * 8);
    int boff[4];                                            // B rows (n)
    #pragma unroll
    for (int j = 0; j < 4; ++j) {
        const int rb = wn * 64 + j * 16 + lr16;
        boff[j] = 1024 + rb * 32 + ((q ^ ((rb >> 1) & 3)) * 8);
    }
    const int rhB = wm * 16 + lr16;                         // H0 row (batch)

    f32x4 acc1[2][4] = {};
    const float rs = rsqrtf(1.0f + 1e-5f);

    for (int nt = 0; nt < 4; ++nt) {
        // ================= phase A =================
        f32x4 acc0[4] = {};
        const u16* pA  = Azb + (size_t)(brow + rS) * KP0 + cA * 8;   // t<128
        const u16* pB0 = W0 + (size_t)(nt * 256 + rS) * KP0 + cA * 8;
        const u16* pB1 = pB0 + (size_t)128 * KP0;

        // prologue: k-steps 0,1 -> slots 0,1 (all slot reads done: nt==0
        // trivially, nt>0 via the barrier ending the previous phase B)
        if (t < 128) GLD16(pA, SM + t * 8);
        GLD16(pB0, SM + 1024 + t * 8);
        GLD16(pB1, SM + 1024 + (t + 512) * 8);
        pA += 32; pB0 += 32; pB1 += 32;
        if (t < 128) GLD16(pA, SM + SLOT + t * 8);
        GLD16(pB0, SM + SLOT + 1024 + t * 8);
        GLD16(pB1, SM + SLOT + 1024 + (t + 512) * 8);
        pA += 32; pB0 += 32; pB1 += 32;

        int cur = 0, stg = 2;
        for (int it = 0; it < 19; ++it) {
            if (wave < 2) { asm volatile("s_waitcnt vmcnt(3)" ::: "memory"); }
            else          { asm volatile("s_waitcnt vmcnt(2)" ::: "memory"); }
            __builtin_amdgcn_s_barrier();
            __builtin_amdgcn_sched_barrier(0);
            const u16* sc = SM + cur * SLOT;
            bf16x8 a0 = *(const bf16x8*)(sc + aoffA);
            bf16x8 f0 = *(const bf16x8*)(sc + boff[0]);
            bf16x8 f1 = *(const bf16x8*)(sc + boff[1]);
            bf16x8 f2 = *(const bf16x8*)(sc + boff[2]);
            bf16x8 f3 = *(const bf16x8*)(sc + boff[3]);
            if (it + 2 < 20) {
                u16* ss = SM + stg * SLOT;
                if (t < 128) GLD16(pA, ss + t * 8);
                GLD16(pB0, ss + 1024 + t * 8);
                GLD16(pB1, ss + 1024 + (t + 512) * 8);
                pA += 32; pB0 += 32; pB1 += 32;
            }
            asm volatile("s_waitcnt lgkmcnt(0)" ::: "memory");
            __builtin_amdgcn_sched_barrier(0);
            __builtin_amdgcn_s_setprio(1);
            acc0[0] = MFMA16(a0, f0, acc0[0]);
            acc0[1] = MFMA16(a0, f1, acc0[1]);
            acc0[2] = MFMA16(a0, f2, acc0[2]);
            acc0[3] = MFMA16(a0, f3, acc0[3]);
            __builtin_amdgcn_s_setprio(0);
            cur = (cur == 2) ? 0 : cur + 1;
            stg = (stg == 2) ? 0 : stg + 1;
        }
        // peel it=19 (data in slot 1)
        asm volatile("s_waitcnt vmcnt(0)" ::: "memory");
        __builtin_amdgcn_s_barrier();
        __builtin_amdgcn_sched_barrier(0);
        {
            const u16* sc = SM + SLOT;
            bf16x8 a0 = *(const bf16x8*)(sc + aoffA);
            bf16x8 f0 = *(const bf16x8*)(sc + boff[0]);
            bf16x8 f1 = *(const bf16x8*)(sc + boff[1]);
            bf16x8 f2 = *(const bf16x8*)(sc + boff[2]);
            bf16x8 f3 = *(const bf16x8*)(sc + boff[3]);
            asm volatile("s_waitcnt lgkmcnt(0)" ::: "memory");
            __builtin_amdgcn_sched_barrier(0);
            __builtin_amdgcn_s_setprio(1);
            acc0[0] = MFMA16(a0, f0, acc0[0]);
            acc0[1] = MFMA16(a0, f1, acc0[1]);
            acc0[2] = MFMA16(a0, f2, acc0[2]);
            acc0[3] = MFMA16(a0, f3, acc0[3]);
            __builtin_amdgcn_s_setprio(0);
        }
        __builtin_amdgcn_s_barrier();   // all waves' slot reads complete

        // phase-B(h=0) prologue BEFORE the h0 epilogue (latency hidden)
        const u16* pC0 = W1 + (size_t)rS * N0 + nt * 256 + cA * 8;
        GLD16(pC0,          SM + 1024 + t * 8);
        GLD16(pC0 + 131072, SM + 1024 + (t + 512) * 8);
        GLD16(pC0 + 32,          SM + SLOT + 1024 + t * 8);
        GLD16(pC0 + 131072 + 32, SM + SLOT + 1024 + (t + 512) * 8);

        // h0 epilogue -> H0 (XOR-swizzled: 16B-chunk ^ (row&7))
        #pragma unroll
        for (int j = 0; j < 4; ++j) {
            const int n = nt * 256 + wn * 64 + j * 16 + lr16;
            const float gg = g0v[n] * rs;
            const float bb = be0v[n];
            const float bi = b0v[n];
            const int col = wn * 64 + j * 16 + lr16;
            float v0 = fmaxf(fmaf(gg, acc0[j][0] + bi, bb), 0.f);
            float v1 = fmaxf(fmaf(gg, acc0[j][1] + bi, bb), 0.f);
            float v2 = fmaxf(fmaf(gg, acc0[j][2] + bi, bb), 0.f);
            float v3 = fmaxf(fmaf(gg, acc0[j][3] + bi, bb), 0.f);
            unsigned pa = cvtpk2(v0, v1);
            unsigned pb = cvtpk2(v2, v3);
            #pragma unroll
            for (int r = 0; r < 4; ++r) {
                const int row = wm * 16 + q * 4 + r;
                const unsigned pk = (r < 2) ? pa : pb;
                const u16 val = (r & 1) ? (u16)(pk >> 16) : (u16)pk;
                H0[row * 256 + (((col >> 3) ^ (row & 7)) * 8) + (col & 7)] = val;
            }
        }
        asm volatile("s_waitcnt lgkmcnt(0)" ::: "memory");
        __builtin_amdgcn_s_barrier();   // H0 ready

        // ================= phase B: two 256-col halves =================
        #pragma unroll
        for (int h = 0; h < 2; ++h) {
            if (h == 1) {
                // previous half's final barrier guarantees slot reads done
                const u16* pCh = W1 + (size_t)(256 + rS) * N0 + nt * 256 + cA * 8;
                GLD16(pCh,          SM + 1024 + t * 8);
                GLD16(pCh + 131072, SM + 1024 + (t + 512) * 8);
                GLD16(pCh + 32,          SM + SLOT + 1024 + t * 8);
                GLD16(pCh + 131072 + 32, SM + SLOT + 1024 + (t + 512) * 8);
            }
            const u16* pCk = W1 + (size_t)(h * 256 + rS) * N0 + nt * 256 + cA * 8 + 64;
            int cb = 0, sb = 2;
            for (int ks = 0; ks < 7; ++ks) {
                asm volatile("s_waitcnt vmcnt(2)" ::: "memory");
                __builtin_amdgcn_s_barrier();
                __builtin_amdgcn_sched_barrier(0);
                const u16* sc = SM + cb * SLOT;
                const int c8 = ks * 4 + q;
                bf16x8 a0 = *(const bf16x8*)(&H0[rhB * 256 + ((c8 ^ (rhB & 7)) * 8)]);
                bf16x8 f0 = *(const bf16x8*)(sc + boff[0]);
                bf16x8 f1 = *(const bf16x8*)(sc + boff[1]);
                bf16x8 f2 = *(const bf16x8*)(sc + boff[2]);
                bf16x8 f3 = *(const bf16x8*)(sc + boff[3]);
                if (ks + 2 < 8) {
                    u16* ss = SM + sb * SLOT;
                    GLD16(pCk,          ss + 1024 + t * 8);
                    GLD16(pCk + 131072, ss + 1024 + (t + 512) * 8);
                    pCk += 32;
                }
                asm volatile("s_waitcnt lgkmcnt(0)" ::: "memory");
                __builtin_amdgcn_sched_barrier(0);
                __builtin_amdgcn_s_setprio(1);
                acc1[h][0] = MFMA16(a0, f0, acc1[h][0]);
                acc1[h][1] = MFMA16(a0, f1, acc1[h][1]);
                acc1[h][2] = MFMA16(a0, f2, acc1[h][2]);
                acc1[h][3] = MFMA16(a0, f3, acc1[h][3]);
                __builtin_amdgcn_s_setprio(0);
                cb = (cb == 2) ? 0 : cb + 1;
                sb = (sb == 2) ? 0 : sb + 1;
            }
            // peel ks=7 (data in slot 1)
            asm volatile("s_waitcnt vmcnt(0)" ::: "memory");
            __builtin_amdgcn_s_barrier();
            __builtin_amdgcn_sched_barrier(0);
            {
                const u16* sc = SM + SLOT;
                const int c8 = 7 * 4 + q;
                bf16x8 a0 = *(const bf16x8*)(&H0[rhB * 256 + ((c8 ^ (rhB & 7)) * 8)]);
                bf16x8 f0 = *(const bf16x8*)(sc + boff[0]);
                bf16x8 f1 = *(const bf16x8*)(sc + boff[1]);
                bf16x8 f2 = *(const bf16x8*)(sc + boff[2]);
                bf16x8 f3 = *(const bf16x8*)(sc + boff[3]);
                asm volatile("s_waitcnt lgkmcnt(0)" ::: "memory");
                __builtin_amdgcn_sched_barrier(0);
                __builtin_amdgcn_s_setprio(1);
                acc1[h][0] = MFMA16(a0, f0, acc1[h][0]);
                acc1[h][1] = MFMA16(a0, f1, acc1[h][1]);
                acc1[h][2] = MFMA16(a0, f2, acc1[h][2]);
                acc1[h][3] = MFMA16(a0, f3, acc1[h][3]);
                __builtin_amdgcn_s_setprio(0);
            }
            __builtin_amdgcn_s_barrier();   // slot reads complete
        }
    }

    // ================= final epilogue =================
    float s[4] = {0.f, 0.f, 0.f, 0.f};
    #pragma unroll
    for (int h = 0; h < 2; ++h)
        #pragma unroll
        for (int j = 0; j < 4; ++j) {
            const int n1 = h * 256 + wn * 64 + j * 16 + lr16;
            const float wv = wov[n1];
            const float gg = g1v[n1] * rs;
            const float bb = be1v[n1];
            const float bi = b1v[n1];
            #pragma unroll
            for (int r = 0; r < 4; ++r) {
                float v = fmaxf(fmaf(gg, acc1[h][j][r] + bi, bb), 0.f);
                s[r] = fmaf(v, wv, s[r]);
            }
        }
    #pragma unroll
    for (int r = 0; r < 4; ++r) {
        float v = s[r];
        v += __shfl_xor(v, 1, 64);
        v += __shfl_xor(v, 2, 64);
        v += __shfl_xor(v, 4, 64);
        v += __shfl_xor(v, 8, 64);
        s[r] = v;
    }
    if (lr16 == 0) {
        #pragma unroll
        for (int r = 0; r < 4; ++r)
            red[wn][wm * 16 + q * 4 + r] = s[r];
    }
    __syncthreads();
    if (t < 32) {
        const float v = red[0][t] + red[1][t] + red[2][t] + red[3][t] + bov[0];
        out[brow + t] = 1.f / (1.f + expf(-v));
    }
}

// ---------------------------------------------------------------------------
extern "C" void kernel_launch(void* const* d_in, const int* in_sizes, int n_in,
                              void* d_out, int out_size, void* d_ws, size_t ws_size,
                              hipStream_t stream)
{
    const int*   x     = (const int*)  d_in[0];
    const float* emb   = (const float*)d_in[1];
    const float* w_c   = (const float*)d_in[2];
    const float* b_c   = (const float*)d_in[3];
    const float* g_c   = (const float*)d_in[4];
    const float* be_c  = (const float*)d_in[5];
    const float* w0    = (const float*)d_in[6];
    const float* b0    = (const float*)d_in[7];
    const float* g0    = (const float*)d_in[8];
    const float* be0   = (const float*)d_in[9];
    const float* w1    = (const float*)d_in[10];
    const float* b1    = (const float*)d_in[11];
    const float* g1    = (const float*)d_in[12];
    const float* be1   = (const float*)d_in[13];
    const float* w_out = (const float*)d_in[14];
    const float* b_out = (const float*)d_in[15];
    float* out = (float*)d_out;

    // workspace layout (~23 MB)
    u16*   zb    = (u16*)d_ws;                          // B*640*2 = 20.97 MB
    u16*   w0b   = zb  + (size_t)B_SZ * KP0;            // 1.31 MB
    u16*   w1b   = w0b + (size_t)N0 * KP0;              // 1.05 MB
    u16*   wcb   = w1b + (size_t)N1 * N0;               // 0.06 MB
    float* bcp   = (float*)(wcb + (size_t)NCP * KP0);
    float* gcp   = bcp + NCP;
    float* becp  = gcp + NCP;

    prep_all_kernel<<<391, 256, 0, stream>>>(
        w0, w1, w_c, b_c, g_c, be_c, w0b, w1b, wcb, bcp, gcp, becp);

    fused_controller_kernel<<<B_SZ / CBR, 256, 0, stream>>>(
        x, emb, wcb, bcp, gcp, becp, zb);

    fused_mlp_kernel<<<B_SZ / 32, 512, 0, stream>>>(
        zb, w0b, w1b, b0, g0, be0, b1, g1, be1, w_out, b_out, out);
}

// Round 10
// 208.426 us; speedup vs baseline: 1.3149x; 1.3149x over previous
//
#include <hip/hip_runtime.h>
#include <math.h>

#define B_SZ 16384
#define F_N 39
#define V_N 30000
#define D_N 16
#define K_SEL 20
#define FD 624     // F_N * D_N
#define KP0 640    // controller/GEMM0 K padded to multiple of 32
#define NCP 48     // controller GEMM padded N (>= 39, 3 n-tiles of 16)
#define N0 1024
#define N1 512
#define CBR 16     // batch rows per fused-controller block
#define ALD 648    // LDS row stride (u16)

typedef unsigned short u16;
typedef __attribute__((ext_vector_type(8))) short bf16x8;
typedef __attribute__((ext_vector_type(8))) unsigned short u16x8;
typedef __attribute__((ext_vector_type(4))) float f32x4;

__device__ __forceinline__ float bf2f(u16 v) {
    union { unsigned u; float f; } x; x.u = ((unsigned)v) << 16;
    return x.f;
}
// HW packed convert: D[15:0]=bf16(a), D[31:16]=bf16(b), RNE.
__device__ __forceinline__ unsigned cvtpk2(float a, float b) {
    unsigned d;
    asm("v_cvt_pk_bf16_f32 %0, %1, %2" : "=v"(d) : "v"(a), "v"(b));
    return d;
}

#define GLD16(gp, lp) __builtin_amdgcn_global_load_lds( \
    (const __attribute__((address_space(1))) unsigned int*)(gp), \
    (__attribute__((address_space(3))) unsigned int*)(lp), 16, 0, 0)

#define MFMA16(a, b, c) __builtin_amdgcn_mfma_f32_16x16x32_bf16((a), (b), (c), 0, 0, 0)

#define SBAR()   __builtin_amdgcn_s_barrier()
#define SCHB()   __builtin_amdgcn_sched_barrier(0)
#define LGKM0()  asm volatile("s_waitcnt lgkmcnt(0)" ::: "memory")
#define PRIO(x)  __builtin_amdgcn_s_setprio(x)

// ---------------------------------------------------------------------------
// prep (coalesced): [0,134) w0/wc permute via LDS; [134,390) w1 convert;
// [390,398) outp zero; 398: bn params.   (r6 proven version)
// ---------------------------------------------------------------------------
__global__ __launch_bounds__(256) void prep_all_kernel(
    const float* __restrict__ w0, const float* __restrict__ w1,
    const float* __restrict__ w_c, const float* __restrict__ b_c,
    const float* __restrict__ g_c, const float* __restrict__ be_c,
    u16* __restrict__ w0b, u16* __restrict__ w1b, u16* __restrict__ wcb,
    float* __restrict__ bcp, float* __restrict__ gcp, float* __restrict__ becp,
    float* __restrict__ outp)
{
    __shared__ float Lb[8][624];
    const int bid = blockIdx.x;
    const int t   = threadIdx.x;

    if (bid < 134) {
        const bool is_w0 = (bid < 128);
        const int r0 = is_w0 ? bid * 8 : (bid - 128) * 8;
        const int nrows_src = is_w0 ? N0 : F_N;
        const float* __restrict__ src = is_w0 ? w0 : w_c;
        u16* __restrict__ dst = is_w0 ? w0b : wcb;

        for (int j = t; j < 8 * 156; j += 256) {
            const int row = j / 156;
            const int c4  = j - row * 156;
            const int n   = r0 + row;
            if (n < nrows_src)
                *(float4*)&Lb[row][c4 * 4] =
                    *(const float4*)&src[(size_t)n * FD + c4 * 4];
        }
        __syncthreads();

        for (int j = t; j < 8 * 320; j += 256) {
            const int row = j / 320;
            const int pr  = j - row * 320;
            const int n   = r0 + row;
            const int k0  = pr * 2;
            float v0 = 0.f, v1 = 0.f;
            if (n < nrows_src) {
                const int d0 = k0 & 15,       f0 = k0 >> 4;
                const int d1 = (k0 + 1) & 15, f1 = (k0 + 1) >> 4;
                if (f0 < F_N) v0 = Lb[row][d0 * F_N + f0];
                if (f1 < F_N) v1 = Lb[row][d1 * F_N + f1];
            }
            *(unsigned*)&dst[(size_t)n * KP0 + k0] = cvtpk2(v0, v1);
        }
        return;
    }
    if (bid < 390) {
        const size_t e0 = (size_t)(bid - 134) * 2048 + t * 8;
        float4 v0 = *(const float4*)(w1 + e0);
        float4 v1 = *(const float4*)(w1 + e0 + 4);
        uint4 o = { cvtpk2(v0.x, v0.y), cvtpk2(v0.z, v0.w),
                    cvtpk2(v1.x, v1.y), cvtpk2(v1.z, v1.w) };
        *(uint4*)(w1b + e0) = o;
        return;
    }
    if (bid < 398) {
        const size_t e0 = (size_t)(bid - 390) * 2048 + t * 8;
        float4 z = {0.f, 0.f, 0.f, 0.f};
        *(float4*)(outp + e0)     = z;
        *(float4*)(outp + e0 + 4) = z;
        return;
    }
    if (t < 3 * NCP) {
        const int which = t / NCP, n = t - which * NCP;
        float v = 0.f;
        if (n < F_N) v = (which == 0) ? b_c[n] : (which == 1) ? g_c[n] : be_c[n];
        ((which == 0) ? bcp : (which == 1) ? gcp : becp)[n] = v;
    }
}

// ---------------------------------------------------------------------------
// Fused controller (r3/r6 proven version, unchanged).
// ---------------------------------------------------------------------------
__global__ __launch_bounds__(256) void fused_controller_kernel(
    const int* __restrict__ x, const float* __restrict__ emb_table,
    const u16* __restrict__ wcb, const float* __restrict__ bcp,
    const float* __restrict__ gcp, const float* __restrict__ becp,
    u16* __restrict__ zb)
{
    __shared__ __align__(16) u16 Al[CBR * ALD];
    __shared__ float vv[CBR][49];
    __shared__ f32x4 part[4][64][3];
    __shared__ float selw[CBR][F_N];

    const int t    = threadIdx.x;
    const int wave = t >> 6;
    const int lane = t & 63;
    const int b0   = blockIdx.x * CBR;

    {
        const int p0 = t, p1 = t + 256, p2 = t + 512;
        const int xi0 = x[b0 * F_N + p0];
        const int xi1 = x[b0 * F_N + p1];
        const int xi2 = (p2 < CBR * F_N) ? x[b0 * F_N + p2] : 0;
        const int pp[3] = { p0, p1, p2 };
        const int xx[3] = { xi0, xi1, xi2 };
        #pragma unroll
        for (int s = 0; s < 3; ++s) {
            const int p = pp[s];
            if (p < CBR * F_N) {
                const int row = p / F_N;
                const int f   = p - row * F_N;
                const float4* src =
                    (const float4*)(emb_table + (size_t)(xx[s] + f * V_N) * D_N);
                float4 v0 = src[0], v1 = src[1], v2 = src[2], v3 = src[3];
                uint4 o0 = { cvtpk2(v0.x, v0.y), cvtpk2(v0.z, v0.w),
                             cvtpk2(v1.x, v1.y), cvtpk2(v1.z, v1.w) };
                uint4 o1 = { cvtpk2(v2.x, v2.y), cvtpk2(v2.z, v2.w),
                             cvtpk2(v3.x, v3.y), cvtpk2(v3.z, v3.w) };
                *(uint4*)&Al[row * ALD + f * D_N]     = o0;
                *(uint4*)&Al[row * ALD + f * D_N + 8] = o1;
            }
        }
    }
    __syncthreads();

    const int m = lane & 15;
    const int q = lane >> 4;
    f32x4 acc0 = {}, acc1 = {}, acc2 = {};
    {
        const u16* ap  = &Al[m * ALD + wave * 160 + q * 8];
        const u16* bp0 = wcb + (size_t)(0  + m) * KP0 + wave * 160 + q * 8;
        const u16* bp1 = wcb + (size_t)(16 + m) * KP0 + wave * 160 + q * 8;
        const u16* bp2 = wcb + (size_t)(32 + m) * KP0 + wave * 160 + q * 8;
        #pragma unroll
        for (int k = 0; k < 5; ++k) {
            bf16x8 af = *(const bf16x8*)ap;
            bf16x8 b0r = *(const bf16x8*)bp0;
            bf16x8 b1r = *(const bf16x8*)bp1;
            bf16x8 b2r = *(const bf16x8*)bp2;
            acc0 = MFMA16(af, b0r, acc0);
            acc1 = MFMA16(af, b1r, acc1);
            acc2 = MFMA16(af, b2r, acc2);
            ap += 32; bp0 += 32; bp1 += 32; bp2 += 32;
        }
    }
    part[wave][lane][0] = acc0;
    part[wave][lane][1] = acc1;
    part[wave][lane][2] = acc2;
    __syncthreads();

    {
        f32x4 r0 = part[0][lane][0] + part[1][lane][0] + part[2][lane][0] + part[3][lane][0];
        f32x4 r1 = part[0][lane][1] + part[1][lane][1] + part[2][lane][1] + part[3][lane][1];
        f32x4 r2 = part[0][lane][2] + part[1][lane][2] + part[2][lane][2] + part[3][lane][2];

        const float rs = rsqrtf(1.0f + 1e-5f);
        if (q == wave) {
            #pragma unroll
            for (int j = 0; j < 3; ++j) {
                const f32x4 a = (j == 0) ? r0 : (j == 1) ? r1 : r2;
                const int n = j * 16 + m;
                const float gn = gcp[n] * rs;
                const float bn = becp[n];
                const float bi = bcp[n];
                #pragma unroll
                for (int r = 0; r < 4; ++r)
                    vv[wave * 4 + r][n] = fmaxf(fmaf(gn, a[r] + bi, bn), 0.f);
            }
        }
    }
    __syncthreads();

    {
        const int row = wave * 4 + (lane >> 4);
        const int fl  = lane & 15;
        float e[3] = {0.f, 0.f, 0.f};
        float mloc = -1e30f;
        #pragma unroll
        for (int it = 0; it < 3; ++it) {
            const int f = fl + 16 * it;
            if (f < F_N) { e[it] = vv[row][f]; mloc = fmaxf(mloc, e[it]); }
        }
        mloc = fmaxf(mloc, __shfl_xor(mloc, 1, 64));
        mloc = fmaxf(mloc, __shfl_xor(mloc, 2, 64));
        mloc = fmaxf(mloc, __shfl_xor(mloc, 4, 64));
        mloc = fmaxf(mloc, __shfl_xor(mloc, 8, 64));
        float sloc = 0.f;
        #pragma unroll
        for (int it = 0; it < 3; ++it) {
            const int f = fl + 16 * it;
            if (f < F_N) { e[it] = expf(e[it] - mloc); sloc += e[it]; }
        }
        sloc += __shfl_xor(sloc, 1, 64);
        sloc += __shfl_xor(sloc, 2, 64);
        sloc += __shfl_xor(sloc, 4, 64);
        sloc += __shfl_xor(sloc, 8, 64);
        const float inv = 1.f / sloc;
        #pragma unroll
        for (int it = 0; it < 3; ++it) {
            const int f = fl + 16 * it;
            if (f < F_N) vv[row][f] = e[it];
        }

        int rank[3] = {};
        for (int gg = 0; gg < F_N; ++gg) {
            const float o = vv[row][gg];
            #pragma unroll
            for (int it = 0; it < 3; ++it) {
                const int f = fl + 16 * it;
                if (f < F_N)
                    rank[it] += (o > e[it] || (o == e[it] && gg < f)) ? 1 : 0;
            }
        }
        #pragma unroll
        for (int it = 0; it < 3; ++it) {
            const int f = fl + 16 * it;
            if (f < F_N)
                selw[row][f] = (rank[it] < K_SEL) ? e[it] * inv : 0.f;
        }
    }
    __syncthreads();

    for (int gp = t; gp < CBR * 40; gp += 256) {
        const int row  = gp / 40;
        const int slot = gp - row * 40;
        u16* dst = zb + (size_t)(b0 + row) * KP0 + slot * D_N;
        uint4 o0 = {0u,0u,0u,0u}, o1 = {0u,0u,0u,0u};
        if (slot < F_N) {
            const float w = selw[row][slot];
            u16x8 a0 = *(u16x8*)&Al[row * ALD + slot * D_N];
            u16x8 a1 = *(u16x8*)&Al[row * ALD + slot * D_N + 8];
            o0 = (uint4){ cvtpk2(bf2f(a0[0]) * w, bf2f(a0[1]) * w),
                          cvtpk2(bf2f(a0[2]) * w, bf2f(a0[3]) * w),
                          cvtpk2(bf2f(a0[4]) * w, bf2f(a0[5]) * w),
                          cvtpk2(bf2f(a0[6]) * w, bf2f(a0[7]) * w) };
            o1 = (uint4){ cvtpk2(bf2f(a1[0]) * w, bf2f(a1[1]) * w),
                          cvtpk2(bf2f(a1[2]) * w, bf2f(a1[3]) * w),
                          cvtpk2(bf2f(a1[4]) * w, bf2f(a1[5]) * w),
                          cvtpk2(bf2f(a1[6]) * w, bf2f(a1[7]) * w) };
        }
        *(uint4*)dst       = o0;
        *(uint4*)(dst + 8) = o1;
    }
}

// ---------------------------------------------------------------------------
// GEMM0, 8-phase template: 256x256 tile, BK=64, 8 waves (2m x 4n, per-wave
// 128x64, acc[8][4]). Double-buffered 128 KB LDS.
// Half-tiles (2 GLD/thread each, issued ADJACENT so vmcnt retires whole ht):
//   ht0 = A rows {0-63,128-191}, ht1 = B rows {0-31,64-95,128-159,192-223},
//   ht2 = B+32 rows, ht3 = A+64 rows.
// Phase reads:  P0 -> ht0+ht1 | P1 -> ht2 | P2 -> ht3 | P3 reg-only.
// Phase stages: P0 -> ht0'    | P1 -> ht1'| P2 -> ht2'| P3 -> ht3'.
// vmcnt accounting (steady): entry P0 = 8 outstanding, need oldest 4 ->
// vmcnt(4); entry P1/P2 = 6, need oldest 2 -> vmcnt(4). Tail: 4/2/0.
// (r9 FAILED because prologue interleaved half-tiles and P0 waited
//  vmcnt(6) -- retired 2 of the 4 loads P0 reads. Fixed here.)
// ---------------------------------------------------------------------------
__global__ __launch_bounds__(512) void gemm0_8ph(
    const u16* __restrict__ A, const u16* __restrict__ W,
    const float* __restrict__ bias, const float* __restrict__ g,
    const float* __restrict__ be, u16* __restrict__ Cout)
{
    __shared__ __align__(16) u16 SM[2 * 32768];   // 128 KB

    const int t    = threadIdx.x;
    const int lane = t & 63;
    const int wave = t >> 6;
    const int wm = wave >> 2, wn = wave & 3;
    const int q = lane >> 4, lr16 = lane & 15;
    const int m0 = blockIdx.x * 256;
    const int n0 = blockIdx.y * 256;

    // staging precompute (per-wave-linear LDS destinations)
    const u16* gA[2]; const u16* gB[2];
    int dA[2], dB[2];
    #pragma unroll
    for (int j = 0; j < 2; ++j) {
        const int c  = t + j * 512;
        const int lr = c >> 3;
        const int ch = c & 7;
        const int chg = ch ^ (lr & 7);          // pre-swizzled global chunk
        const int rA = lr + (lr & 64);          // {0-63,128-191}
        const int rB = (lr & 31) + ((lr >> 5) << 6);
        gA[j] = A + (size_t)(m0 + rA) * KP0 + chg * 8;
        gB[j] = W + (size_t)(n0 + rB) * KP0 + chg * 8;
        dA[j] = rA * 64 + ch * 8;
        dB[j] = 16384 + rB * 64 + ch * 8;
    }

    int aoff[4][2], boff[4][2];
    #pragma unroll
    for (int f = 0; f < 4; ++f)
        #pragma unroll
        for (int k = 0; k < 2; ++k) {
            const int ra = wm * 128 + f * 16 + lr16;
            aoff[f][k] = ra * 64 + (((k * 4 + q) ^ (lr16 & 7)) * 8);
            const int rb = wn * 64 + f * 16 + lr16;
            boff[f][k] = 16384 + rb * 64 + (((k * 4 + q) ^ (lr16 & 7)) * 8);
        }

    // prologue: kt0's 4 half-tiles into buf0, HALF-TILE-MAJOR issue order
    GLD16(gA[0],            SM + dA[0]);
    GLD16(gA[1],            SM + dA[1]);          // ht0
    GLD16(gB[0],            SM + dB[0]);
    GLD16(gB[1],            SM + dB[1]);          // ht1
    GLD16(gB[0] + 32 * KP0, SM + dB[0] + 2048);
    GLD16(gB[1] + 32 * KP0, SM + dB[1] + 2048);   // ht2
    GLD16(gA[0] + 64 * KP0, SM + dA[0] + 4096);
    GLD16(gA[1] + 64 * KP0, SM + dA[1] + 4096);   // ht3

    f32x4 acc[8][4] = {};
    bf16x8 aR[4][2], bR[4][2];

    for (int kt = 0; kt < 10; ++kt) {
        const u16* sb = SM + (kt & 1) * 32768;
        u16* nb = SM + ((kt & 1) ^ 1) * 32768;
        const int ko = (kt + 1) * 64;
        const bool more = (kt + 1 < 10);

        // ---- P0: reads ht0 (A-h0) + ht1 (B n0-1) ----
        asm volatile("s_waitcnt vmcnt(4)" ::: "memory");
        SBAR(); SCHB();
        #pragma unroll
        for (int f = 0; f < 4; ++f)
            #pragma unroll
            for (int k = 0; k < 2; ++k)
                aR[f][k] = *(const bf16x8*)(sb + aoff[f][k]);
        #pragma unroll
        for (int f = 0; f < 2; ++f)
            #pragma unroll
            for (int k = 0; k < 2; ++k)
                bR[f][k] = *(const bf16x8*)(sb + boff[f][k]);
        if (more) {
            GLD16(gA[0] + ko, nb + dA[0]);
            GLD16(gA[1] + ko, nb + dA[1]);        // stage ht0'
        }
        LGKM0(); SCHB(); PRIO(1);
        #pragma unroll
        for (int f = 0; f < 4; ++f)
            #pragma unroll
            for (int n = 0; n < 2; ++n) {
                acc[f][n] = MFMA16(aR[f][0], bR[n][0], acc[f][n]);
                acc[f][n] = MFMA16(aR[f][1], bR[n][1], acc[f][n]);
            }
        PRIO(0);

        // ---- P1: reads ht2 (B n2-3) ----
        if (more) { asm volatile("s_waitcnt vmcnt(4)" ::: "memory"); }
        else      { asm volatile("s_waitcnt vmcnt(2)" ::: "memory"); }
        SBAR(); SCHB();
        #pragma unroll
        for (int f = 0; f < 2; ++f)
            #pragma unroll
            for (int k = 0; k < 2; ++k)
                bR[2 + f][k] = *(const bf16x8*)(sb + boff[2 + f][k]);
        if (more) {
            GLD16(gB[0] + ko, nb + dB[0]);
            GLD16(gB[1] + ko, nb + dB[1]);        // stage ht1'
        }
        LGKM0(); SCHB(); PRIO(1);
        #pragma unroll
        for (int f = 0; f < 4; ++f)
            #pragma unroll
            for (int n = 0; n < 2; ++n) {
                acc[f][2 + n] = MFMA16(aR[f][0], bR[2 + n][0], acc[f][2 + n]);
                acc[f][2 + n] = MFMA16(aR[f][1], bR[2 + n][1], acc[f][2 + n]);
            }
        PRIO(0);

        // ---- P2: reads ht3 (A-h1) ----
        if (more) { asm volatile("s_waitcnt vmcnt(4)" ::: "memory"); }
        else      { asm volatile("s_waitcnt vmcnt(0)" ::: "memory"); }
        SBAR(); SCHB();
        #pragma unroll
        for (int f = 0; f < 4; ++f)
            #pragma unroll
            for (int k = 0; k < 2; ++k)
                aR[f][k] = *(const bf16x8*)(sb + aoff[f][k] + 4096);
        if (more) {
            GLD16(gB[0] + 32 * KP0 + ko, nb + dB[0] + 2048);
            GLD16(gB[1] + 32 * KP0 + ko, nb + dB[1] + 2048);   // stage ht2'
        }
        LGKM0(); SCHB(); PRIO(1);
        #pragma unroll
        for (int f = 0; f < 4; ++f)
            #pragma unroll
            for (int n = 0; n < 2; ++n) {
                acc[4 + f][2 + n] = MFMA16(aR[f][0], bR[2 + n][0], acc[4 + f][2 + n]);
                acc[4 + f][2 + n] = MFMA16(aR[f][1], bR[2 + n][1], acc[4 + f][2 + n]);
            }
        PRIO(0);

        // ---- P3: reg-only (bR n0-1 still live) ----
        if (more) {
            GLD16(gA[0] + 64 * KP0 + ko, nb + dA[0] + 4096);
            GLD16(gA[1] + 64 * KP0 + ko, nb + dA[1] + 4096);   // stage ht3'
        }
        PRIO(1);
        #pragma unroll
        for (int f = 0; f < 4; ++f)
            #pragma unroll
            for (int n = 0; n < 2; ++n) {
                acc[4 + f][n] = MFMA16(aR[f][0], bR[n][0], acc[4 + f][n]);
                acc[4 + f][n] = MFMA16(aR[f][1], bR[n][1], acc[4 + f][n]);
            }
        PRIO(0);
    }

    // ---- epilogue: bn+relu+cvt_pk, LDS-staged coalesced stores ----
    const float rs = rsqrtf(1.0f + 1e-5f);
    __syncthreads();
    u16* Cs = SM;                      // 128 x 264 u16 = 67584 B
    #pragma unroll
    for (int rho = 0; rho < 2; ++rho) {
        if (wm == rho) {
            #pragma unroll
            for (int nf = 0; nf < 4; ++nf) {
                const int nl = wn * 64 + nf * 16 + lr16;
                const int n  = n0 + nl;
                const float bn_g = g[n] * rs;
                const float bn_b = be[n];
                const float bi   = bias[n];
                #pragma unroll
                for (int mf = 0; mf < 8; ++mf) {
                    const int rb = mf * 16 + q * 4;
                    float v0 = fmaxf(fmaf(bn_g, acc[mf][nf][0] + bi, bn_b), 0.f);
                    float v1 = fmaxf(fmaf(bn_g, acc[mf][nf][1] + bi, bn_b), 0.f);
                    float v2 = fmaxf(fmaf(bn_g, acc[mf][nf][2] + bi, bn_b), 0.f);
                    float v3 = fmaxf(fmaf(bn_g, acc[mf][nf][3] + bi, bn_b), 0.f);
                    unsigned pa = cvtpk2(v0, v1);
                    unsigned pb = cvtpk2(v2, v3);
                    Cs[(rb + 0) * 264 + nl] = (u16)pa;
                    Cs[(rb + 1) * 264 + nl] = (u16)(pa >> 16);
                    Cs[(rb + 2) * 264 + nl] = (u16)pb;
                    Cs[(rb + 3) * 264 + nl] = (u16)(pb >> 16);
                }
            }
        }
        __syncthreads();
        #pragma unroll
        for (int s = 0; s < 8; ++s) {
            const int chunk = s * 512 + t;       // 0..4095
            const int row   = chunk >> 5;        // 128 rows
            const int col   = (chunk & 31) << 3;
            *(u16x8*)&Cout[(size_t)(m0 + rho * 128 + row) * N0 + n0 + col] =
                *(const u16x8*)&Cs[row * 264 + col];
        }
        __syncthreads();
    }
}

// ---------------------------------------------------------------------------
// GEMM1 (fused w_out reduce): 256x128 tile, BK=64, K=1024 (16 kt), 8 waves
// (2m x 4n, per-wave 128x32, acc[8][2]). 96 KB LDS.
// Half-tiles: ht0 = A rows {0-63,128-191}, ht1 = B (all 128), ht2 = A+64.
// Phase reads:  P0 -> ht0+ht1 | P1 -> ht2.
// Phase stages: P0 -> ht0',ht1' | P1 -> ht2'.
// vmcnt: entry P0 = 6, need oldest 4 -> vmcnt(2); entry P1 = 6, need
// oldest 2 -> vmcnt(4). Tail: 2/0.
// Epilogue: bn1/relu, w_out dot, shuffle reduce, atomicAdd outp.
// ---------------------------------------------------------------------------
__global__ __launch_bounds__(512) void gemm1_8ph(
    const u16* __restrict__ A, const u16* __restrict__ W,
    const float* __restrict__ bias, const float* __restrict__ g,
    const float* __restrict__ be,
    const float* __restrict__ w_out, float* __restrict__ outp)
{
    __shared__ __align__(16) u16 SM[2 * 24576];   // 96 KB

    const int t    = threadIdx.x;
    const int lane = t & 63;
    const int wave = t >> 6;
    const int wm = wave >> 2, wn = wave & 3;
    const int q = lane >> 4, lr16 = lane & 15;
    const int m0 = blockIdx.x * 256;
    const int n0 = blockIdx.y * 128;

    const u16* gA[2]; const u16* gB[2];
    int dA[2], dB[2];
    #pragma unroll
    for (int j = 0; j < 2; ++j) {
        const int c  = t + j * 512;
        const int lr = c >> 3;
        const int ch = c & 7;
        const int chg = ch ^ (lr & 7);
        const int rA = lr + (lr & 64);
        gA[j] = A + (size_t)(m0 + rA) * N0 + chg * 8;
        gB[j] = W + (size_t)(n0 + lr) * N0 + chg * 8;
        dA[j] = rA * 64 + ch * 8;
        dB[j] = 16384 + lr * 64 + ch * 8;
    }

    int aoff[4][2], boff[2][2];
    #pragma unroll
    for (int f = 0; f < 4; ++f)
        #pragma unroll
        for (int k = 0; k < 2; ++k) {
            const int ra = wm * 128 + f * 16 + lr16;
            aoff[f][k] = ra * 64 + (((k * 4 + q) ^ (lr16 & 7)) * 8);
        }
    #pragma unroll
    for (int f = 0; f < 2; ++f)
        #pragma unroll
        for (int k = 0; k < 2; ++k) {
            const int rb = wn * 32 + f * 16 + lr16;
            boff[f][k] = 16384 + rb * 64 + (((k * 4 + q) ^ (lr16 & 7)) * 8);
        }

    // prologue: kt0's 3 half-tiles into buf0, HALF-TILE-MAJOR issue order
    GLD16(gA[0],           SM + dA[0]);
    GLD16(gA[1],           SM + dA[1]);           // ht0
    GLD16(gB[0],           SM + dB[0]);
    GLD16(gB[1],           SM + dB[1]);           // ht1
    GLD16(gA[0] + 64 * N0, SM + dA[0] + 4096);
    GLD16(gA[1] + 64 * N0, SM + dA[1] + 4096);    // ht2

    f32x4 acc[8][2] = {};
    bf16x8 aR[4][2], bR[2][2];

    for (int kt = 0; kt < 16; ++kt) {
        const u16* sb = SM + (kt & 1) * 24576;
        u16* nb = SM + ((kt & 1) ^ 1) * 24576;
        const int ko = (kt + 1) * 64;
        const bool more = (kt + 1 < 16);

        // ---- P0: reads ht0 (A-h0) + ht1 (B) ----
        asm volatile("s_waitcnt vmcnt(2)" ::: "memory");
        SBAR(); SCHB();
        #pragma unroll
        for (int f = 0; f < 4; ++f)
            #pragma unroll
            for (int k = 0; k < 2; ++k)
                aR[f][k] = *(const bf16x8*)(sb + aoff[f][k]);
        #pragma unroll
        for (int f = 0; f < 2; ++f)
            #pragma unroll
            for (int k = 0; k < 2; ++k)
                bR[f][k] = *(const bf16x8*)(sb + boff[f][k]);
        if (more) {
            GLD16(gA[0] + ko, nb + dA[0]);
            GLD16(gA[1] + ko, nb + dA[1]);        // stage ht0'
            GLD16(gB[0] + ko, nb + dB[0]);
            GLD16(gB[1] + ko, nb + dB[1]);        // stage ht1'
        }
        LGKM0(); SCHB(); PRIO(1);
        #pragma unroll
        for (int f = 0; f < 4; ++f)
            #pragma unroll
            for (int n = 0; n < 2; ++n) {
                acc[f][n] = MFMA16(aR[f][0], bR[n][0], acc[f][n]);
                acc[f][n] = MFMA16(aR[f][1], bR[n][1], acc[f][n]);
            }
        PRIO(0);

        // ---- P1: reads ht2 (A-h1) ----
        if (more) { asm volatile("s_waitcnt vmcnt(4)" ::: "memory"); }
        else      { asm volatile("s_waitcnt vmcnt(0)" ::: "memory"); }
        SBAR(); SCHB();
        #pragma unroll
        for (int f = 0; f < 4; ++f)
            #pragma unroll
            for (int k = 0; k < 2; ++k)
                aR[f][k] = *(const bf16x8*)(sb + aoff[f][k] + 4096);
        if (more) {
            GLD16(gA[0] + 64 * N0 + ko, nb + dA[0] + 4096);
            GLD16(gA[1] + 64 * N0 + ko, nb + dA[1] + 4096);    // stage ht2'
        }
        LGKM0(); SCHB(); PRIO(1);
        #pragma unroll
        for (int f = 0; f < 4; ++f)
            #pragma unroll
            for (int n = 0; n < 2; ++n) {
                acc[4 + f][n] = MFMA16(aR[f][0], bR[n][0], acc[4 + f][n]);
                acc[4 + f][n] = MFMA16(aR[f][1], bR[n][1], acc[4 + f][n]);
            }
        PRIO(0);
    }

    // ---- epilogue ----
    const float rs = rsqrtf(1.0f + 1e-5f);
    float s[8][4] = {};
    #pragma unroll
    for (int nf = 0; nf < 2; ++nf) {
        const int n = n0 + wn * 32 + nf * 16 + lr16;
        const float bn_g = g[n] * rs;
        const float bn_b = be[n];
        const float bi   = bias[n];
        const float wo   = w_out[n];
        #pragma unroll
        for (int mf = 0; mf < 8; ++mf)
            #pragma unroll
            for (int r = 0; r < 4; ++r) {
                float v = fmaxf(fmaf(bn_g, acc[mf][nf][r] + bi, bn_b), 0.f);
                s[mf][r] = fmaf(v, wo, s[mf][r]);
            }
    }
    #pragma unroll
    for (int mf = 0; mf < 8; ++mf)
        #pragma unroll
        for (int r = 0; r < 4; ++r) {
            float v = s[mf][r];
            v += __shfl_xor(v, 1, 64);
            v += __shfl_xor(v, 2, 64);
            v += __shfl_xor(v, 4, 64);
            v += __shfl_xor(v, 8, 64);
            s[mf][r] = v;
        }
    if (lr16 == 0) {
        #pragma unroll
        for (int mf = 0; mf < 8; ++mf)
            #pragma unroll
            for (int r = 0; r < 4; ++r)
                atomicAdd(&outp[m0 + wm * 128 + mf * 16 + q * 4 + r], s[mf][r]);
    }
}

// ---------------------------------------------------------------------------
// out[b] = sigmoid(outp[b] + b_out)
// ---------------------------------------------------------------------------
__global__ __launch_bounds__(256) void sigmoid_kernel(
    const float* __restrict__ outp, const float* __restrict__ b_out,
    float* __restrict__ out)
{
    const int b = blockIdx.x * 256 + threadIdx.x;
    out[b] = 1.f / (1.f + expf(-(outp[b] + b_out[0])));
}

// ---------------------------------------------------------------------------
extern "C" void kernel_launch(void* const* d_in, const int* in_sizes, int n_in,
                              void* d_out, int out_size, void* d_ws, size_t ws_size,
                              hipStream_t stream)
{
    const int*   x     = (const int*)  d_in[0];
    const float* emb   = (const float*)d_in[1];
    const float* w_c   = (const float*)d_in[2];
    const float* b_c   = (const float*)d_in[3];
    const float* g_c   = (const float*)d_in[4];
    const float* be_c  = (const float*)d_in[5];
    const float* w0    = (const float*)d_in[6];
    const float* b0    = (const float*)d_in[7];
    const float* g0    = (const float*)d_in[8];
    const float* be0   = (const float*)d_in[9];
    const float* w1    = (const float*)d_in[10];
    const float* b1    = (const float*)d_in[11];
    const float* g1    = (const float*)d_in[12];
    const float* be1   = (const float*)d_in[13];
    const float* w_out = (const float*)d_in[14];
    const float* b_out = (const float*)d_in[15];
    float* out = (float*)d_out;

    // workspace layout (~57 MB)
    u16*   zb    = (u16*)d_ws;                          // B*640*2  = 20.97 MB
    u16*   w0b   = zb    + (size_t)B_SZ * KP0;          // 1.31 MB
    u16*   h0b   = w0b   + (size_t)N0 * KP0;            // 33.55 MB
    u16*   w1b   = h0b   + (size_t)B_SZ * N0;           // 1.05 MB
    u16*   wcb   = w1b   + (size_t)N1 * N0;             // 0.06 MB
    float* outp  = (float*)(wcb + (size_t)NCP * KP0);   // 64 KB
    float* bcp   = outp + B_SZ;
    float* gcp   = bcp + NCP;
    float* becp  = gcp + NCP;

    prep_all_kernel<<<399, 256, 0, stream>>>(
        w0, w1, w_c, b_c, g_c, be_c, w0b, w1b, wcb, bcp, gcp, becp, outp);

    fused_controller_kernel<<<B_SZ / CBR, 256, 0, stream>>>(
        x, emb, wcb, bcp, gcp, becp, zb);

    gemm0_8ph<<<dim3(B_SZ / 256, N0 / 256), 512, 0, stream>>>(
        zb, w0b, b0, g0, be0, h0b);

    gemm1_8ph<<<dim3(B_SZ / 256, N1 / 128), 512, 0, stream>>>(
        h0b, w1b, b1, g1, be1, w_out, outp);

    sigmoid_kernel<<<B_SZ / 256, 256, 0, stream>>>(outp, b_out, out);
}